// Round 4
// baseline (595.945 us; speedup 1.0000x reference)
//
#include <hip/hip_runtime.h>

typedef __attribute__((ext_vector_type(8))) short short8;
typedef __attribute__((ext_vector_type(4))) float f32x4;
typedef __attribute__((ext_vector_type(4))) int i32x4;

#define LOG2E 1.44269504f

__device__ __forceinline__ short f2bf(float f) {
  unsigned u = __builtin_bit_cast(unsigned, f);
  u += 0x7fffu + ((u >> 16) & 1u);   // round-to-nearest-even
  return (short)(u >> 16);
}

// ---------------- kernel A: w1 = W@a1, w2 = W@a2 (fp32) ----------------
__global__ void gat_wvec(const float* __restrict__ W, const float* __restrict__ a1,
                         const float* __restrict__ a2, float* __restrict__ w1,
                         float* __restrict__ w2) {
  __shared__ float a1f[256], a2f[256];
  const int tid = threadIdx.x;
  a1f[tid] = a1[tid];
  a2f[tid] = a2[tid];
  __syncthreads();
  float s1 = 0.f, s2 = 0.f;
  const float4* wr = (const float4*)(W + (size_t)tid * 256);
  for (int d0 = 0; d0 < 64; ++d0) {
    float4 v = wr[d0];
    s1 += v.x * a1f[d0 * 4] + v.y * a1f[d0 * 4 + 1] + v.z * a1f[d0 * 4 + 2] + v.w * a1f[d0 * 4 + 3];
    s2 += v.x * a2f[d0 * 4] + v.y * a2f[d0 * 4 + 1] + v.z * a2f[d0 * 4 + 2] + v.w * a2f[d0 * 4 + 3];
  }
  w1[tid] = s1;
  w2[tid] = s2;
}

// ------------- f32 -> bf16 convert + transpose: dst[b][c][r] = bf16(src[b][r][c]) -------------
__global__ void convT(const float* __restrict__ src, short* __restrict__ dst,
                      int R, int C) {
  __shared__ short T[64][72];
  const int tid = threadIdx.x;
  const int bc = blockIdx.x, br = blockIdx.y, bb = blockIdx.z;
  const float* s = src + (size_t)bb * R * C;
  short* d = dst + (size_t)bb * R * C;
  const int rr = tid >> 2, cc = (tid & 3) << 4;
  const float4* sp = (const float4*)(s + (size_t)(br * 64 + rr) * C + bc * 64 + cc);
  alignas(16) short v[16];
#pragma unroll
  for (int g = 0; g < 4; ++g) {
    float4 x = sp[g];
    v[g * 4 + 0] = f2bf(x.x);
    v[g * 4 + 1] = f2bf(x.y);
    v[g * 4 + 2] = f2bf(x.z);
    v[g * 4 + 3] = f2bf(x.w);
  }
  *(short8*)&T[rr][cc] = *(short8*)&v[0];
  *(short8*)&T[rr][cc + 8] = *(short8*)&v[8];
  __syncthreads();
#pragma unroll
  for (int j = 0; j < 16; ++j) v[j] = T[cc + j][rr];
  short8* dp = (short8*)(d + (size_t)(bc * 64 + rr) * R + br * 64 + cc);
  dp[0] = *(short8*)&v[0];
  dp[1] = *(short8*)&v[8];
}

// ------- kernel B: AxL/AyL = (feat @ w1|w2) * LOG2E  (log2-domain scores) -------
__global__ void gat_axay(const float* __restrict__ feat, const float* __restrict__ w1,
                         const float* __restrict__ w2, float* __restrict__ AxL,
                         float* __restrict__ AyL) {
  const int lane = threadIdx.x & 63;
  const int row = blockIdx.x * 4 + (threadIdx.x >> 6);
  float4 fv = *(const float4*)(feat + (size_t)row * 256 + lane * 4);
  const float4 w1v = *(const float4*)(w1 + lane * 4);
  const float4 w2v = *(const float4*)(w2 + lane * 4);
  float s1 = fv.x * w1v.x + fv.y * w1v.y + fv.z * w1v.z + fv.w * w1v.w;
  float s2 = fv.x * w2v.x + fv.y * w2v.y + fv.z * w2v.z + fv.w * w2v.w;
#pragma unroll
  for (int off = 32; off >= 1; off >>= 1) {
    s1 += __shfl_xor(s1, off);
    s2 += __shfl_xor(s2, off);
  }
  if (lane == 0) { AxL[row] = s1 * LOG2E; AyL[row] = s2 * LOG2E; }
}

// ---------------- kernel B2: per-batch max of AxL ----------------
__global__ void gat_max(const float* __restrict__ AxL, float* __restrict__ MbL) {
  __shared__ float red[256];
  const int b = blockIdx.x, tid = threadIdx.x;
  float m = -3.4e38f;
  for (int i = tid; i < 4096; i += 256) m = fmaxf(m, AxL[b * 4096 + i]);
  red[tid] = m;
  __syncthreads();
  for (int s = 128; s > 0; s >>= 1) {
    if (tid < s) red[tid] = fmaxf(red[tid], red[tid + s]);
    __syncthreads();
  }
  if (tid == 0) MbL[b] = red[0];
}

// -------- kernel P: pack adj (int32 {0,1}) into bitmask [4][4096][128] uint32 --------
// Pure streaming pass: 268 MB read -> 8 MB write. Each thread builds one word
// from 32 consecutive ints via 8 independent nontemporal b128 loads.
__global__ void gat_pack(const int* __restrict__ adj, unsigned* __restrict__ bmk) {
  const size_t widx = (size_t)blockIdx.x * 256 + threadIdx.x;
  const i32x4* p = (const i32x4*)(adj + widx * 32);
  unsigned wv = 0;
#pragma unroll
  for (int g = 0; g < 8; ++g) {
    i32x4 v = __builtin_nontemporal_load(p + g);
#pragma unroll
    for (int u = 0; u < 4; ++u)
      wv |= ((unsigned)v[u]) << (g * 4 + u);   // adj values are {0,1} per setup
  }
  bmk[widx] = wv;
}

// -------- kernel C: fused softmax(mask(lrelu(rank1)))@feat @W +ELU --------
// grid 512, XCD-pinned batch: featT[b] (2 MB) + bmk[b] (2 MB) L2-resident.
// Block = 4 waves, 32-row i-tile, full j-range in 32 chunks of 128.
// All inner-loop loads are L2-hot; prefetch is issued AFTER the barrier so the
// compiler's vmcnt(0)-before-s_barrier drain cannot expose it.
__global__ __launch_bounds__(256, 2) void gat_attn(
    const short* __restrict__ featT,  // [4][256][4096] bf16
    const unsigned* __restrict__ bmk, // [4][4096][128]
    const float* __restrict__ AxL, const float* __restrict__ AyL,
    const float* __restrict__ MbL,
    const short* __restrict__ WT,     // [256][256] bf16 (W^T)
    float* __restrict__ out)          // [4][4096][256] f32
{
  __shared__ short smem[8704];  // Pbuf [2][32][136] (stride 272B=17x16); aliased as hbuf[32][264]

  const int tid = threadIdx.x;
  const int blk = blockIdx.x;
  const int x = blk & 7;
  const int b = x >> 1;                       // XCD-pinned batch
  const int it = ((blk >> 3) << 1) | (x & 1); // 0..127
  const int i0 = it << 5;

  const int r = tid >> 3;            // local row 0..31 (8 threads/row)
  const int cg = tid & 7;            // 16-j group within 128-chunk
  const int c0 = cg << 4;

  const float ayL = AyL[b * 4096 + i0 + r];
  const float sL = ayL + MbL[b];
  const float mrL = fmaxf(sL, 0.2f * sL);   // log2-domain uniform row upper bound
  const float aL = ayL - mrL;               // v = AxL[j] + aL
  const float dd = -0.8f * mrL;             // u = max(v, 0.2v + dd)

  const int lane = tid & 63;
  const int w = tid >> 6;
  const int n0 = w << 6;
  const int l15 = lane & 15;
  const int q = lane >> 4;

  f32x4 acc[2][4], lac[2];
#pragma unroll
  for (int i = 0; i < 2; ++i) {
    lac[i] = (f32x4){0.f, 0.f, 0.f, 0.f};
#pragma unroll
    for (int j = 0; j < 4; ++j) acc[i][j] = (f32x4){0.f, 0.f, 0.f, 0.f};
  }

  short8 ones;
#pragma unroll
  for (int j = 0; j < 8; ++j) ones[j] = (short)0x3F80;  // bf16 1.0

  const float4* axp = (const float4*)(AxL + b * 4096 + c0);
  const unsigned* bmp = bmk + ((size_t)(b * 4096 + i0 + r)) * 128 + (cg >> 1);
  const short* ftb = featT + ((size_t)(b * 256 + n0 + l15)) * 4096 + q * 8;
  const int sh = (cg & 1) << 4;

  float4 axv[4];
  unsigned bw = bmp[0];
#pragma unroll
  for (int g = 0; g < 4; ++g) axv[g] = axp[g];

  for (int jc = 0; jc < 32; ++jc) {
    const int buf = (jc & 1) * 4352;
    // ---- phase 1: 16 probabilities -> bf16 pairs via v_perm, LDS b128 writes ----
    const unsigned bloc = bw >> sh;
    unsigned pw[8];
#pragma unroll
    for (int g = 0; g < 4; ++g) {
      const float* af = (const float*)&axv[g];
      unsigned pr[4];
#pragma unroll
      for (int u = 0; u < 4; ++u) {
        const int k = g * 4 + u;
        float v = af[u] + aL;
        float uu = fmaxf(v, fmaf(0.2f, v, dd));
        int m = (int)(bloc << (31 - k)) >> 31;            // all-ones if adj bit set
        unsigned ub = ((unsigned)m & __builtin_bit_cast(unsigned, uu)) |
                      (~(unsigned)m & 0xFF800000u);       // else -inf -> exp2 = 0
        float p = __builtin_amdgcn_exp2f(__builtin_bit_cast(float, ub));
        pr[u] = __builtin_bit_cast(unsigned, p) + 0x8000u; // round-to-nearest bf16
      }
      pw[g * 2]     = __builtin_amdgcn_perm(pr[1], pr[0], 0x07060302u);
      pw[g * 2 + 1] = __builtin_amdgcn_perm(pr[3], pr[2], 0x07060302u);
    }
    {
      uint4* dst = (uint4*)(smem + buf + r * 136 + c0);
      dst[0] = *(uint4*)&pw[0];
      dst[1] = *(uint4*)&pw[4];
    }
    __syncthreads();

    // prefetch next chunk's mask/Ax (L2-hot, lands during MFMA, consumed pre-barrier)
    if (jc < 31) {
      bw = bmp[(jc + 1) * 4];
#pragma unroll
      for (int g = 0; g < 4; ++g) axv[g] = axp[(jc + 1) * 32 + g];
    }

    // ---- phase 2: MFMA  acc += P(32x128) @ feat-slice; lac += P @ ones ----
    const int j0 = jc << 7;
#pragma unroll
    for (int k0 = 0; k0 < 128; k0 += 32) {
      short8 a0 = *(const short8*)(smem + buf + l15 * 136 + k0 + q * 8);
      short8 a1 = *(const short8*)(smem + buf + (16 + l15) * 136 + k0 + q * 8);
      lac[0] = __builtin_amdgcn_mfma_f32_16x16x32_bf16(a0, ones, lac[0], 0, 0, 0);
      lac[1] = __builtin_amdgcn_mfma_f32_16x16x32_bf16(a1, ones, lac[1], 0, 0, 0);
#pragma unroll
      for (int ct = 0; ct < 4; ++ct) {
        short8 bfr = *(const short8*)(ftb + (size_t)ct * 16 * 4096 + j0 + k0);
        acc[0][ct] = __builtin_amdgcn_mfma_f32_16x16x32_bf16(a0, bfr, acc[0][ct], 0, 0, 0);
        acc[1][ct] = __builtin_amdgcn_mfma_f32_16x16x32_bf16(a1, bfr, acc[1][ct], 0, 0, 0);
      }
    }
  }

  // lac[rt][reg] holds the row-sum l for exactly the rows this lane's acc owns
  float linv[2][4];
#pragma unroll
  for (int rt = 0; rt < 2; ++rt)
#pragma unroll
    for (int reg = 0; reg < 4; ++reg) {
      float l = lac[rt][reg];
      linv[rt][reg] = l > 0.f ? 1.f / l : 0.f;
    }

  __syncthreads();   // all Pbuf reads done before aliasing smem as hbuf
  short* hbuf = smem;  // [32][264] (stride 528B = 33x16)
#pragma unroll
  for (int rt = 0; rt < 2; ++rt)
#pragma unroll
    for (int reg = 0; reg < 4; ++reg) {
      const int lr = rt * 16 + q * 4 + reg;   // C/D layout: row = quad*4 + reg
#pragma unroll
      for (int ct = 0; ct < 4; ++ct)
        hbuf[lr * 264 + n0 + ct * 16 + l15] = f2bf(acc[rt][ct][reg] * linv[rt][reg]);
    }
  __syncthreads();

  // ---- epilogue GEMM: (32x256) @ W -> 32x256, ELU, store ----
#pragma unroll
  for (int i = 0; i < 2; ++i)
#pragma unroll
    for (int j = 0; j < 4; ++j) acc[i][j] = (f32x4){0.f, 0.f, 0.f, 0.f};

#pragma unroll 2
  for (int k0 = 0; k0 < 256; k0 += 32) {
    short8 afr0 = *(const short8*)&hbuf[l15 * 264 + k0 + q * 8];
    short8 afr1 = *(const short8*)&hbuf[(16 + l15) * 264 + k0 + q * 8];
#pragma unroll
    for (int ct = 0; ct < 4; ++ct) {
      short8 bfr = *(const short8*)(WT + (size_t)(n0 + ct * 16 + l15) * 256 + k0 + q * 8);
      acc[0][ct] = __builtin_amdgcn_mfma_f32_16x16x32_bf16(afr0, bfr, acc[0][ct], 0, 0, 0);
      acc[1][ct] = __builtin_amdgcn_mfma_f32_16x16x32_bf16(afr1, bfr, acc[1][ct], 0, 0, 0);
    }
  }

#pragma unroll
  for (int rt = 0; rt < 2; ++rt)
#pragma unroll
    for (int reg = 0; reg < 4; ++reg) {
      const int row = i0 + rt * 16 + q * 4 + reg;
      float* orow = out + ((size_t)(b * 4096 + row)) * 256 + n0 + l15;
#pragma unroll
      for (int ct = 0; ct < 4; ++ct) {
        float v = acc[rt][ct][reg];
        float o = v > 0.f ? v : (__builtin_amdgcn_exp2f(v * LOG2E) - 1.f);
        __builtin_nontemporal_store(o, orow + ct * 16);
      }
    }
}

extern "C" void kernel_launch(void* const* d_in, const int* in_sizes, int n_in,
                              void* d_out, int out_size, void* d_ws, size_t ws_size,
                              hipStream_t stream) {
  (void)in_sizes; (void)n_in; (void)out_size; (void)ws_size;
  const float* feat = (const float*)d_in[0];
  const int* adj = (const int*)d_in[1];
  const float* W = (const float*)d_in[2];
  const float* a1 = (const float*)d_in[3];
  const float* a2 = (const float*)d_in[4];
  float* out = (float*)d_out;

  char* ws = (char*)d_ws;
  short* featT   = (short*)ws;                     // 8,388,608 B [4][256][4096] bf16
  unsigned* bmk  = (unsigned*)(ws + 8388608);      // 8,388,608 B [4][4096][128] u32
  short* WT      = (short*)(ws + 16777216);        // 131,072 B
  float* AxL     = (float*)(ws + 16908288);        // 64 KB
  float* AyL     = (float*)(ws + 16973824);        // 64 KB
  float* MbL     = (float*)(ws + 17039360);        // 16 B
  float* w1      = (float*)(ws + 17040384);        // 1 KB
  float* w2      = (float*)(ws + 17041408);        // 1 KB

  hipLaunchKernelGGL(gat_pack, dim3(8192), dim3(256), 0, stream, adj, bmk);
  hipLaunchKernelGGL(gat_wvec, dim3(1), dim3(256), 0, stream, W, a1, a2, w1, w2);
  hipLaunchKernelGGL(convT, dim3(4, 4, 1), dim3(256), 0, stream, W, WT, 256, 256);
  hipLaunchKernelGGL(convT, dim3(4, 64, 4), dim3(256), 0, stream, feat, featT, 4096, 256);
  hipLaunchKernelGGL(gat_axay, dim3(4096), dim3(256), 0, stream, feat, w1, w2, AxL, AyL);
  hipLaunchKernelGGL(gat_max, dim3(4), dim3(256), 0, stream, AxL, MbL);
  hipLaunchKernelGGL(gat_attn, dim3(512), dim3(256), 0, stream, featT, bmk, AxL, AyL, MbL, WT, out);
}

// Round 5
// 476.300 us; speedup vs baseline: 1.2512x; 1.2512x over previous
//
#include <hip/hip_runtime.h>

typedef __attribute__((ext_vector_type(8))) short short8;
typedef __attribute__((ext_vector_type(4))) float f32x4;
typedef __attribute__((ext_vector_type(4))) int i32x4;

#define LOG2E 1.44269504f
#define FT_STRIDE 4128            // featT row stride in elements: 8256 B, NOT a multiple of 256 -> L2 channel spread
#define FT_BATCH (256 * FT_STRIDE)

__device__ __forceinline__ short f2bf(float f) {
  unsigned u = __builtin_bit_cast(unsigned, f);
  u += 0x7fffu + ((u >> 16) & 1u);   // round-to-nearest-even
  return (short)(u >> 16);
}

// ---------------- kernel A: w1 = W@a1, w2 = W@a2 (fp32) ----------------
__global__ void gat_wvec(const float* __restrict__ W, const float* __restrict__ a1,
                         const float* __restrict__ a2, float* __restrict__ w1,
                         float* __restrict__ w2) {
  __shared__ float a1f[256], a2f[256];
  const int tid = threadIdx.x;
  a1f[tid] = a1[tid];
  a2f[tid] = a2[tid];
  __syncthreads();
  float s1 = 0.f, s2 = 0.f;
  const float4* wr = (const float4*)(W + (size_t)tid * 256);
  for (int d0 = 0; d0 < 64; ++d0) {
    float4 v = wr[d0];
    s1 += v.x * a1f[d0 * 4] + v.y * a1f[d0 * 4 + 1] + v.z * a1f[d0 * 4 + 2] + v.w * a1f[d0 * 4 + 3];
    s2 += v.x * a2f[d0 * 4] + v.y * a2f[d0 * 4 + 1] + v.z * a2f[d0 * 4 + 2] + v.w * a2f[d0 * 4 + 3];
  }
  w1[tid] = s1;
  w2[tid] = s2;
}

// ---- f32 -> bf16 convert + transpose: dst[b][c][r] = bf16(src[b][r][c]), padded dst stride ----
__global__ void convT(const float* __restrict__ src, short* __restrict__ dst,
                      int R, int C, int dstStride, size_t dstBatch) {
  __shared__ short T[64][72];
  const int tid = threadIdx.x;
  const int bc = blockIdx.x, br = blockIdx.y, bb = blockIdx.z;
  const float* s = src + (size_t)bb * R * C;
  short* d = dst + (size_t)bb * dstBatch;
  const int rr = tid >> 2, cc = (tid & 3) << 4;
  const float4* sp = (const float4*)(s + (size_t)(br * 64 + rr) * C + bc * 64 + cc);
  alignas(16) short v[16];
#pragma unroll
  for (int g = 0; g < 4; ++g) {
    float4 x = sp[g];
    v[g * 4 + 0] = f2bf(x.x);
    v[g * 4 + 1] = f2bf(x.y);
    v[g * 4 + 2] = f2bf(x.z);
    v[g * 4 + 3] = f2bf(x.w);
  }
  *(short8*)&T[rr][cc] = *(short8*)&v[0];
  *(short8*)&T[rr][cc + 8] = *(short8*)&v[8];
  __syncthreads();
#pragma unroll
  for (int j = 0; j < 16; ++j) v[j] = T[cc + j][rr];
  short8* dp = (short8*)(d + (size_t)(bc * 64 + rr) * dstStride + br * 64 + cc);
  dp[0] = *(short8*)&v[0];
  dp[1] = *(short8*)&v[8];
}

// ------- kernel B: AxL/AyL = (feat @ w1|w2) * LOG2E  (log2-domain scores) -------
__global__ void gat_axay(const float* __restrict__ feat, const float* __restrict__ w1,
                         const float* __restrict__ w2, float* __restrict__ AxL,
                         float* __restrict__ AyL) {
  const int lane = threadIdx.x & 63;
  const int row = blockIdx.x * 4 + (threadIdx.x >> 6);
  float4 fv = *(const float4*)(feat + (size_t)row * 256 + lane * 4);
  const float4 w1v = *(const float4*)(w1 + lane * 4);
  const float4 w2v = *(const float4*)(w2 + lane * 4);
  float s1 = fv.x * w1v.x + fv.y * w1v.y + fv.z * w1v.z + fv.w * w1v.w;
  float s2 = fv.x * w2v.x + fv.y * w2v.y + fv.z * w2v.z + fv.w * w2v.w;
#pragma unroll
  for (int off = 32; off >= 1; off >>= 1) {
    s1 += __shfl_xor(s1, off);
    s2 += __shfl_xor(s2, off);
  }
  if (lane == 0) { AxL[row] = s1 * LOG2E; AyL[row] = s2 * LOG2E; }
}

// ---------------- kernel B2: per-batch max of AxL ----------------
__global__ void gat_max(const float* __restrict__ AxL, float* __restrict__ MbL) {
  __shared__ float red[256];
  const int b = blockIdx.x, tid = threadIdx.x;
  float m = -3.4e38f;
  for (int i = tid; i < 4096; i += 256) m = fmaxf(m, AxL[b * 4096 + i]);
  red[tid] = m;
  __syncthreads();
  for (int s = 128; s > 0; s >>= 1) {
    if (tid < s) red[tid] = fmaxf(red[tid], red[tid + s]);
    __syncthreads();
  }
  if (tid == 0) MbL[b] = m = red[0];
}

// -------- kernel C: fused softmax(mask(lrelu(rank1)))@feat @W +ELU --------
// grid 512 (2 blocks/CU), block 512 thr = 8 waves -> 16 waves/CU. Wave owns 32
// D-cols (B-frag gathers halved/wave). 32-row i-tile, full j in 32 chunks of 128.
// adj is streamed directly from HBM (nontemporal, prefetch issued just after the
// barrier, consumed before the next barrier). featT rows padded to 4128 elems.
__global__ __launch_bounds__(512, 4) void gat_attn(
    const short* __restrict__ featT,  // [4][256][4128] bf16 (4096 valid cols)
    const int* __restrict__ adj,      // [4][4096][4096]
    const float* __restrict__ AxL, const float* __restrict__ AyL,
    const float* __restrict__ MbL,
    const short* __restrict__ WT,     // [256][256] bf16 (W^T)
    float* __restrict__ out)          // [4][4096][256] f32
{
  __shared__ short smem[8704];  // Pbuf [2][32][136]; aliased later as hbuf[32][264]

  const int tid = threadIdx.x;
  const int blk = blockIdx.x;
  const int x = blk & 7;
  const int b = x >> 1;                       // XCD-pinned batch
  const int it = ((blk >> 3) << 1) | (x & 1); // 0..127
  const int i0 = it << 5;

  const int r = tid >> 4;            // local row 0..31 (16 threads/row)
  const int cg = tid & 15;           // 8-j group within 128-chunk

  const float ayL = AyL[b * 4096 + i0 + r];
  const float sL = ayL + MbL[b];
  const float mrL = fmaxf(sL, 0.2f * sL);   // log2-domain uniform row upper bound
  const float aL = ayL - mrL;               // v = AxL[j] + aL
  const float dd = -0.8f * mrL;             // u = max(v, 0.2v + dd)

  const int lane = tid & 63;
  const int w = tid >> 6;            // 0..7
  const int n0 = w << 5;             // 32 cols per wave
  const int l15 = lane & 15;
  const int q = lane >> 4;

  f32x4 acc[2][2], lac[2];
#pragma unroll
  for (int i = 0; i < 2; ++i) {
    lac[i] = (f32x4){0.f, 0.f, 0.f, 0.f};
#pragma unroll
    for (int j = 0; j < 2; ++j) acc[i][j] = (f32x4){0.f, 0.f, 0.f, 0.f};
  }

  short8 ones;
#pragma unroll
  for (int j = 0; j < 8; ++j) ones[j] = (short)0x3F80;  // bf16 1.0

  const i32x4* adjp = (const i32x4*)(adj + ((size_t)(b * 4096 + i0 + r)) * 4096) + cg * 2;
  const float4* axp = (const float4*)(AxL + b * 4096) + cg * 2;
  const short* ftb = featT + ((size_t)b * FT_BATCH) + (size_t)(n0 + l15) * FT_STRIDE + q * 8;

  i32x4 adv[2];
  float4 axv[2];
  adv[0] = __builtin_nontemporal_load(adjp);
  adv[1] = __builtin_nontemporal_load(adjp + 1);
  axv[0] = axp[0];
  axv[1] = axp[1];

  for (int jc = 0; jc < 32; ++jc) {
    const int buf = (jc & 1) * 4352;
    // ---- phase 1: 8 probabilities -> 4 packed bf16-pair words, one b128 LDS write ----
    unsigned pw[4];
#pragma unroll
    for (int g = 0; g < 2; ++g) {
      const float* af = (const float*)&axv[g];
      unsigned pr[4];
#pragma unroll
      for (int u = 0; u < 4; ++u) {
        float v = af[u] + aL;
        float uu = fmaxf(v, fmaf(0.2f, v, dd));
        unsigned ub = adv[g][u] > 0 ? __builtin_bit_cast(unsigned, uu) : 0xFF800000u;
        float p = __builtin_amdgcn_exp2f(__builtin_bit_cast(float, ub));
        pr[u] = __builtin_bit_cast(unsigned, p) + 0x8000u;  // bf16 round in high half
      }
      pw[g * 2]     = __builtin_amdgcn_perm(pr[1], pr[0], 0x07060302u);
      pw[g * 2 + 1] = __builtin_amdgcn_perm(pr[3], pr[2], 0x07060302u);
    }
    *(uint4*)(smem + buf + r * 136 + cg * 8) = *(uint4*)pw;
    __syncthreads();

    // prefetch next chunk's adj (HBM, nontemporal) + Ax (L2-hot); lands during MFMA
    if (jc < 31) {
      adv[0] = __builtin_nontemporal_load(adjp + (jc + 1) * 32);
      adv[1] = __builtin_nontemporal_load(adjp + (jc + 1) * 32 + 1);
      axv[0] = axp[(jc + 1) * 32];
      axv[1] = axp[(jc + 1) * 32 + 1];
    }

    // ---- phase 2: MFMA  acc += P(32x128) @ feat-slice(128 x 32cols); lac += P @ ones ----
    const int j0 = jc << 7;
#pragma unroll
    for (int k0 = 0; k0 < 128; k0 += 32) {
      short8 a0 = *(const short8*)(smem + buf + l15 * 136 + k0 + q * 8);
      short8 a1 = *(const short8*)(smem + buf + (16 + l15) * 136 + k0 + q * 8);
      lac[0] = __builtin_amdgcn_mfma_f32_16x16x32_bf16(a0, ones, lac[0], 0, 0, 0);
      lac[1] = __builtin_amdgcn_mfma_f32_16x16x32_bf16(a1, ones, lac[1], 0, 0, 0);
#pragma unroll
      for (int ct = 0; ct < 2; ++ct) {
        short8 bfr = *(const short8*)(ftb + (size_t)ct * 16 * FT_STRIDE + j0 + k0);
        acc[0][ct] = __builtin_amdgcn_mfma_f32_16x16x32_bf16(a0, bfr, acc[0][ct], 0, 0, 0);
        acc[1][ct] = __builtin_amdgcn_mfma_f32_16x16x32_bf16(a1, bfr, acc[1][ct], 0, 0, 0);
      }
    }
  }

  // lac[rt][reg] = row-sum l for exactly the rows this lane's acc owns
  float linv[2][4];
#pragma unroll
  for (int rt = 0; rt < 2; ++rt)
#pragma unroll
    for (int reg = 0; reg < 4; ++reg) {
      float l = lac[rt][reg];
      linv[rt][reg] = l > 0.f ? 1.f / l : 0.f;
    }

  __syncthreads();   // all Pbuf reads done before aliasing smem as hbuf
  short* hbuf = smem;  // [32][264]
#pragma unroll
  for (int rt = 0; rt < 2; ++rt)
#pragma unroll
    for (int reg = 0; reg < 4; ++reg) {
      const int lr = rt * 16 + q * 4 + reg;   // C/D layout: row = quad*4 + reg
#pragma unroll
      for (int ct = 0; ct < 2; ++ct)
        hbuf[lr * 264 + n0 + ct * 16 + l15] = f2bf(acc[rt][ct][reg] * linv[rt][reg]);
    }
  __syncthreads();

  // ---- epilogue GEMM: (32x256) @ W -> 32 x (32 cols per wave), ELU, store ----
  f32x4 ac2[2][2];
#pragma unroll
  for (int i = 0; i < 2; ++i)
#pragma unroll
    for (int j = 0; j < 2; ++j) ac2[i][j] = (f32x4){0.f, 0.f, 0.f, 0.f};

#pragma unroll 2
  for (int k0 = 0; k0 < 256; k0 += 32) {
    short8 afr0 = *(const short8*)&hbuf[l15 * 264 + k0 + q * 8];
    short8 afr1 = *(const short8*)&hbuf[(16 + l15) * 264 + k0 + q * 8];
#pragma unroll
    for (int ct = 0; ct < 2; ++ct) {
      short8 bfr = *(const short8*)(WT + (size_t)(n0 + ct * 16 + l15) * 256 + k0 + q * 8);
      ac2[0][ct] = __builtin_amdgcn_mfma_f32_16x16x32_bf16(afr0, bfr, ac2[0][ct], 0, 0, 0);
      ac2[1][ct] = __builtin_amdgcn_mfma_f32_16x16x32_bf16(afr1, bfr, ac2[1][ct], 0, 0, 0);
    }
  }

#pragma unroll
  for (int rt = 0; rt < 2; ++rt)
#pragma unroll
    for (int reg = 0; reg < 4; ++reg) {
      const int row = i0 + rt * 16 + q * 4 + reg;
      float* orow = out + ((size_t)(b * 4096 + row)) * 256 + n0 + l15;
#pragma unroll
      for (int ct = 0; ct < 2; ++ct) {
        float v = ac2[rt][ct][reg];
        float o = v > 0.f ? v : (__builtin_amdgcn_exp2f(v * LOG2E) - 1.f);
        __builtin_nontemporal_store(o, orow + ct * 16);
      }
    }
}

extern "C" void kernel_launch(void* const* d_in, const int* in_sizes, int n_in,
                              void* d_out, int out_size, void* d_ws, size_t ws_size,
                              hipStream_t stream) {
  (void)in_sizes; (void)n_in; (void)out_size; (void)ws_size;
  const float* feat = (const float*)d_in[0];
  const int* adj = (const int*)d_in[1];
  const float* W = (const float*)d_in[2];
  const float* a1 = (const float*)d_in[3];
  const float* a2 = (const float*)d_in[4];
  float* out = (float*)d_out;

  char* ws = (char*)d_ws;
  short* featT   = (short*)ws;                     // 4*256*4128*2 = 8,454,144 B
  short* WT      = (short*)(ws + 8454144);         // 131,072 B
  float* AxL     = (float*)(ws + 8585216);         // 64 KB
  float* AyL     = (float*)(ws + 8650752);         // 64 KB
  float* MbL     = (float*)(ws + 8716288);         // 16 B
  float* w1      = (float*)(ws + 8717312);         // 1 KB
  float* w2      = (float*)(ws + 8718336);         // 1 KB

  hipLaunchKernelGGL(gat_wvec, dim3(1), dim3(256), 0, stream, W, a1, a2, w1, w2);
  hipLaunchKernelGGL(convT, dim3(4, 4, 1), dim3(256), 0, stream, W, WT, 256, 256, 256, (size_t)65536);
  hipLaunchKernelGGL(convT, dim3(4, 64, 4), dim3(256), 0, stream, feat, featT, 4096, 256, FT_STRIDE, (size_t)FT_BATCH);
  hipLaunchKernelGGL(gat_axay, dim3(4096), dim3(256), 0, stream, feat, w1, w2, AxL, AyL);
  hipLaunchKernelGGL(gat_max, dim3(4), dim3(256), 0, stream, AxL, MbL);
  hipLaunchKernelGGL(gat_attn, dim3(512), dim3(512), 0, stream, featT, adj, AxL, AyL, MbL, WT, out);
}

// Round 6
// 466.586 us; speedup vs baseline: 1.2772x; 1.0208x over previous
//
#include <hip/hip_runtime.h>

typedef __attribute__((ext_vector_type(8))) short short8;
typedef __attribute__((ext_vector_type(4))) float f32x4;
typedef __attribute__((ext_vector_type(4))) int i32x4;
typedef __attribute__((ext_vector_type(2))) unsigned u32x2;

#define LOG2E 1.44269504f
#define FT_STRIDE 4128            // featT row stride (8256 B, not mult of 256 -> L2 channel spread)
#define FT_BATCH (256 * FT_STRIDE)

__device__ __forceinline__ short f2bf(float f) {
  unsigned u = __builtin_bit_cast(unsigned, f);
  u += 0x7fffu + ((u >> 16) & 1u);   // round-to-nearest-even
  return (short)(u >> 16);
}

// ---------------- kernel A: w1 = W@a1, w2 = W@a2 (fp32) ----------------
__global__ void gat_wvec(const float* __restrict__ W, const float* __restrict__ a1,
                         const float* __restrict__ a2, float* __restrict__ w1,
                         float* __restrict__ w2) {
  __shared__ float a1f[256], a2f[256];
  const int tid = threadIdx.x;
  a1f[tid] = a1[tid];
  a2f[tid] = a2[tid];
  __syncthreads();
  float s1 = 0.f, s2 = 0.f;
  const float4* wr = (const float4*)(W + (size_t)tid * 256);
  for (int d0 = 0; d0 < 64; ++d0) {
    float4 v = wr[d0];
    s1 += v.x * a1f[d0 * 4] + v.y * a1f[d0 * 4 + 1] + v.z * a1f[d0 * 4 + 2] + v.w * a1f[d0 * 4 + 3];
    s2 += v.x * a2f[d0 * 4] + v.y * a2f[d0 * 4 + 1] + v.z * a2f[d0 * 4 + 2] + v.w * a2f[d0 * 4 + 3];
  }
  w1[tid] = s1;
  w2[tid] = s2;
}

// ---- f32 -> bf16 convert + transpose: dst[b][c][r] = bf16(src[b][r][c]), padded dst stride ----
__global__ void convT(const float* __restrict__ src, short* __restrict__ dst,
                      int R, int C, int dstStride, size_t dstBatch) {
  __shared__ short T[64][72];
  const int tid = threadIdx.x;
  const int bc = blockIdx.x, br = blockIdx.y, bb = blockIdx.z;
  const float* s = src + (size_t)bb * R * C;
  short* d = dst + (size_t)bb * dstBatch;
  const int rr = tid >> 2, cc = (tid & 3) << 4;
  const float4* sp = (const float4*)(s + (size_t)(br * 64 + rr) * C + bc * 64 + cc);
  alignas(16) short v[16];
#pragma unroll
  for (int g = 0; g < 4; ++g) {
    float4 x = sp[g];
    v[g * 4 + 0] = f2bf(x.x);
    v[g * 4 + 1] = f2bf(x.y);
    v[g * 4 + 2] = f2bf(x.z);
    v[g * 4 + 3] = f2bf(x.w);
  }
  *(short8*)&T[rr][cc] = *(short8*)&v[0];
  *(short8*)&T[rr][cc + 8] = *(short8*)&v[8];
  __syncthreads();
#pragma unroll
  for (int j = 0; j < 16; ++j) v[j] = T[cc + j][rr];
  short8* dp = (short8*)(d + (size_t)(bc * 64 + rr) * dstStride + br * 64 + cc);
  dp[0] = *(short8*)&v[0];
  dp[1] = *(short8*)&v[8];
}

// ------- kernel B: AxL/AyL = (feat @ w1|w2) * LOG2E  (log2-domain scores) -------
__global__ void gat_axay(const float* __restrict__ feat, const float* __restrict__ w1,
                         const float* __restrict__ w2, float* __restrict__ AxL,
                         float* __restrict__ AyL) {
  const int lane = threadIdx.x & 63;
  const int row = blockIdx.x * 4 + (threadIdx.x >> 6);
  float4 fv = *(const float4*)(feat + (size_t)row * 256 + lane * 4);
  const float4 w1v = *(const float4*)(w1 + lane * 4);
  const float4 w2v = *(const float4*)(w2 + lane * 4);
  float s1 = fv.x * w1v.x + fv.y * w1v.y + fv.z * w1v.z + fv.w * w1v.w;
  float s2 = fv.x * w2v.x + fv.y * w2v.y + fv.z * w2v.z + fv.w * w2v.w;
#pragma unroll
  for (int off = 32; off >= 1; off >>= 1) {
    s1 += __shfl_xor(s1, off);
    s2 += __shfl_xor(s2, off);
  }
  if (lane == 0) { AxL[row] = s1 * LOG2E; AyL[row] = s2 * LOG2E; }
}

// ---------------- kernel B2: per-batch max of AxL ----------------
__global__ void gat_max(const float* __restrict__ AxL, float* __restrict__ MbL) {
  __shared__ float red[256];
  const int b = blockIdx.x, tid = threadIdx.x;
  float m = -3.4e38f;
  for (int i = tid; i < 4096; i += 256) m = fmaxf(m, AxL[b * 4096 + i]);
  red[tid] = m;
  __syncthreads();
  for (int s = 128; s > 0; s >>= 1) {
    if (tid < s) red[tid] = fmaxf(red[tid], red[tid + s]);
    __syncthreads();
  }
  if (tid == 0) MbL[b] = red[0];
}

// -------- kernel C: fused softmax(mask(lrelu(rank1)))@feat @W +ELU --------
// Block 512 thr = 8 waves; 32-row i-tile; j in 64 chunks of 64. Per chunk the
// block stages featT[:, j..j+64] (32 KB) into an XOR-swizzled LDS slab with
// COALESCED global reads (8 rows x 128 B per wave-instr), kills the 16-way
// scattered B-gather of the previous version. P tile + B slab double-buffered
// -> one barrier per chunk; adj/Ax/featT prefetch issued right after it.
// LDS 74,752 B/block -> 2 blocks/CU. grid 512, XCD-pinned batch.
__global__ __launch_bounds__(512, 4) void gat_attn(
    const short* __restrict__ featT,  // [4][256][4128] bf16 (4096 valid cols)
    const int* __restrict__ adj,      // [4][4096][4096]
    const float* __restrict__ AxL, const float* __restrict__ AyL,
    const float* __restrict__ MbL,
    const short* __restrict__ WT,     // [256][256] bf16 (W^T)
    float* __restrict__ out)          // [4][4096][256] f32
{
  // shorts: Bslab [2][256][64] swizzled @ 0 (65,536 B); Pbuf [2][32][72] @ 32768 (9,216 B)
  __shared__ short smem[37376];

  const int tid = threadIdx.x;
  const int blk = blockIdx.x;
  const int x = blk & 7;
  const int b = x >> 1;                       // XCD-pinned batch
  const int it = ((blk >> 3) << 1) | (x & 1); // 0..127
  const int i0 = it << 5;

  // --- P-producer role: thread owns (row pi, 4 j's) ---
  const int pi = tid >> 4;           // 0..31
  const int pj = tid & 15;           // j-quad index
  const float ayL = AyL[b * 4096 + i0 + pi];
  const float sL = ayL + MbL[b];
  const float mrL = fmaxf(sL, 0.2f * sL);   // log2-domain uniform row upper bound
  const float aL = ayL - mrL;
  const float dd = -0.8f * mrL;

  // --- stager role: 4 segments, 16 B each, rows sn+64k ---
  const int sn = tid >> 3;           // 0..63
  const int so = tid & 7;            // 16-B unit within 64-j row
  const int sph = ((so ^ (sn & 7)) << 3);   // swizzled unit offset (shorts)

  // --- MFMA role ---
  const int lane = tid & 63;
  const int w = tid >> 6;
  const int rowg = (w & 1) << 4;     // 0 / 16
  const int colg = (w >> 1) << 6;    // 0,64,128,192
  const int l15 = lane & 15;
  const int q = lane >> 4;
  const int swz = l15 & 7;
  const int bu0 = (q ^ swz) << 3;          // swizzled k-offset (shorts) for k0=0
  const int bu1 = ((q + 4) ^ swz) << 3;    // for k0=32

  f32x4 acc[4], lac;
  lac = (f32x4){0.f, 0.f, 0.f, 0.f};
#pragma unroll
  for (int j = 0; j < 4; ++j) acc[j] = (f32x4){0.f, 0.f, 0.f, 0.f};

  short8 ones;
#pragma unroll
  for (int j = 0; j < 8; ++j) ones[j] = (short)0x3F80;  // bf16 1.0

  const i32x4* adjp = (const i32x4*)(adj + ((size_t)(b * 4096 + i0 + pi)) * 4096) + pj;
  const float4* axp = (const float4*)(AxL + b * 4096) + pj;
  const short* ftb = featT + (size_t)b * FT_BATCH + (size_t)sn * FT_STRIDE + so * 8;

  i32x4 adv;
  float4 axv;
  short8 bv[4];
  adv = __builtin_nontemporal_load(adjp);
  axv = axp[0];
#pragma unroll
  for (int k = 0; k < 4; ++k) bv[k] = *(const short8*)(ftb + (size_t)k * 64 * FT_STRIDE);

  for (int jc = 0; jc < 64; ++jc) {
    const int pb = jc & 1;
    // ---- phase 1a: 4 probs -> 2 packed bf16-pair words -> ds_write_b64 ----
    {
      const float* af = (const float*)&axv;
      unsigned pr[4];
#pragma unroll
      for (int u = 0; u < 4; ++u) {
        float v = af[u] + aL;
        float uu = fmaxf(v, fmaf(0.2f, v, dd));
        unsigned ub = adv[u] > 0 ? __builtin_bit_cast(unsigned, uu) : 0xFF800000u;
        float p = __builtin_amdgcn_exp2f(__builtin_bit_cast(float, ub));
        pr[u] = __builtin_bit_cast(unsigned, p) + 0x8000u;
      }
      u32x2 pw;
      pw[0] = __builtin_amdgcn_perm(pr[1], pr[0], 0x07060302u);
      pw[1] = __builtin_amdgcn_perm(pr[3], pr[2], 0x07060302u);
      *(u32x2*)(smem + 32768 + pb * 2304 + pi * 72 + pj * 4) = pw;
    }
    // ---- phase 1b: write staged featT slab (swizzled) ----
    {
      short* bs = smem + pb * 16384;
#pragma unroll
      for (int k = 0; k < 4; ++k)
        *(short8*)(bs + (sn + 64 * k) * 64 + sph) = bv[k];
    }
    __syncthreads();

    // ---- prefetch chunk jc+1 (adj HBM first, then L2-hot ax/featT) ----
    if (jc < 63) {
      adv = __builtin_nontemporal_load(adjp + (jc + 1) * 16);
      axv = axp[(jc + 1) * 16];
#pragma unroll
      for (int k = 0; k < 4; ++k)
        bv[k] = *(const short8*)(ftb + (size_t)k * 64 * FT_STRIDE + (jc + 1) * 64);
    }

    // ---- phase 2: MFMA from LDS only ----
    const short* pbuf = smem + 32768 + pb * 2304;
    const short* bsr = smem + pb * 16384;
#pragma unroll
    for (int h = 0; h < 2; ++h) {
      const int k0 = h * 32;
      const int bu = h ? bu1 : bu0;
      short8 a = *(const short8*)(pbuf + (rowg + l15) * 72 + k0 + q * 8);
      lac = __builtin_amdgcn_mfma_f32_16x16x32_bf16(a, ones, lac, 0, 0, 0);
#pragma unroll
      for (int ct = 0; ct < 4; ++ct) {
        short8 bf = *(const short8*)(bsr + (colg + ct * 16 + l15) * 64 + bu);
        acc[ct] = __builtin_amdgcn_mfma_f32_16x16x32_bf16(a, bf, acc[ct], 0, 0, 0);
      }
    }
  }

  // lac[reg] = row-sum for row rowg + q*4 + reg (C/D layout)
  float linv[4];
#pragma unroll
  for (int reg = 0; reg < 4; ++reg) {
    float l = lac[reg];
    linv[reg] = l > 0.f ? 1.f / l : 0.f;
  }

  __syncthreads();   // all slab/P reads done before aliasing smem as hbuf
  short* hbuf = smem;  // [32][264]
#pragma unroll
  for (int reg = 0; reg < 4; ++reg) {
    const int lr = rowg + q * 4 + reg;
#pragma unroll
    for (int ct = 0; ct < 4; ++ct)
      hbuf[lr * 264 + colg + ct * 16 + l15] = f2bf(acc[ct][reg] * linv[reg]);
  }
  __syncthreads();

  // ---- epilogue GEMM: (32x256) @ W, ELU, store ----
  f32x4 ac2[4];
#pragma unroll
  for (int j = 0; j < 4; ++j) ac2[j] = (f32x4){0.f, 0.f, 0.f, 0.f};

#pragma unroll 2
  for (int k0 = 0; k0 < 256; k0 += 32) {
    short8 a = *(const short8*)&hbuf[(rowg + l15) * 264 + k0 + q * 8];
#pragma unroll
    for (int ct = 0; ct < 4; ++ct) {
      short8 bf = *(const short8*)(WT + (size_t)(colg + ct * 16 + l15) * 256 + k0 + q * 8);
      ac2[ct] = __builtin_amdgcn_mfma_f32_16x16x32_bf16(a, bf, ac2[ct], 0, 0, 0);
    }
  }

#pragma unroll
  for (int reg = 0; reg < 4; ++reg) {
    const int row = i0 + rowg + q * 4 + reg;
    float* orow = out + ((size_t)(b * 4096 + row)) * 256 + colg + l15;
#pragma unroll
    for (int ct = 0; ct < 4; ++ct) {
      float v = ac2[ct][reg];
      float o = v > 0.f ? v : (__builtin_amdgcn_exp2f(v * LOG2E) - 1.f);
      __builtin_nontemporal_store(o, orow + ct * 16);
    }
  }
}

extern "C" void kernel_launch(void* const* d_in, const int* in_sizes, int n_in,
                              void* d_out, int out_size, void* d_ws, size_t ws_size,
                              hipStream_t stream) {
  (void)in_sizes; (void)n_in; (void)out_size; (void)ws_size;
  const float* feat = (const float*)d_in[0];
  const int* adj = (const int*)d_in[1];
  const float* W = (const float*)d_in[2];
  const float* a1 = (const float*)d_in[3];
  const float* a2 = (const float*)d_in[4];
  float* out = (float*)d_out;

  char* ws = (char*)d_ws;
  short* featT   = (short*)ws;                     // 4*256*4128*2 = 8,454,144 B
  short* WT      = (short*)(ws + 8454144);         // 131,072 B
  float* AxL     = (float*)(ws + 8585216);         // 64 KB
  float* AyL     = (float*)(ws + 8650752);         // 64 KB
  float* MbL     = (float*)(ws + 8716288);         // 16 B
  float* w1      = (float*)(ws + 8717312);         // 1 KB
  float* w2      = (float*)(ws + 8718336);         // 1 KB

  hipLaunchKernelGGL(gat_wvec, dim3(1), dim3(256), 0, stream, W, a1, a2, w1, w2);
  hipLaunchKernelGGL(convT, dim3(4, 4, 1), dim3(256), 0, stream, W, WT, 256, 256, 256, (size_t)65536);
  hipLaunchKernelGGL(convT, dim3(4, 64, 4), dim3(256), 0, stream, feat, featT, 4096, 256, FT_STRIDE, (size_t)FT_BATCH);
  hipLaunchKernelGGL(gat_axay, dim3(4096), dim3(256), 0, stream, feat, w1, w2, AxL, AyL);
  hipLaunchKernelGGL(gat_max, dim3(4), dim3(256), 0, stream, AxL, MbL);
  hipLaunchKernelGGL(gat_attn, dim3(512), dim3(512), 0, stream, featT, adj, AxL, AyL, MbL, WT, out);
}